// Round 15
// baseline (286.462 us; speedup 1.0000x reference)
//
#include <hip/hip_runtime.h>
#include <hip/hip_bf16.h>
#include <math.h>

// Problem constants
#define BATCH   2048
#define TWO_B   4096
#define DIM     1024
#define NBLK4   256           // 16x16 grid of 256x256 tiles
// 1 / (0.07 * ln(2)) : exp(s/T) = exp2(s * INV_T_LOG2E)
#define INV_T_LOG2E 20.60991907f
#define INV_T       14.285714285714286f
#define SCALE_ONE   0x7F7F7F7F   // E8M0 unity scale in every byte

typedef float f32x4 __attribute__((ext_vector_type(4)));
typedef int   v8i   __attribute__((ext_vector_type(8)));

__device__ __forceinline__ void load_lds16(const void* g, void* l) {
    __builtin_amdgcn_global_load_lds(
        (const __attribute__((address_space(1))) void*)g,
        (__attribute__((address_space(3))) void*)l,
        16, 0, 0);
}

// ---------------------------------------------------------------------------
// Kernel 1: L2-normalize 4096 rows -> fp8 e4m3 z[4096][1024] (4 MB).
// Wave-per-row; zero-inits rowsum + completion counter. No fences.
// ---------------------------------------------------------------------------
__global__ __launch_bounds__(256) void normalize_kernel(
        const float* __restrict__ feat, char* __restrict__ z,
        float* __restrict__ rowsum, unsigned int* __restrict__ counter) {
    const int lane = threadIdx.x & 63;
    const int row  = blockIdx.x * 4 + (threadIdx.x >> 6);
    if (lane == 0) rowsum[row] = 0.0f;
    if (blockIdx.x == 0 && threadIdx.x == 0) *counter = 0u;

    const float* src = feat + (row < BATCH ? (size_t)row * (2 * DIM)
                                           : (size_t)(row - BATCH) * (2 * DIM) + DIM);
    float4 v[4];
    float ss = 0.0f;
    #pragma unroll
    for (int t = 0; t < 4; ++t) {
        v[t] = ((const float4*)src)[t * 64 + lane];
        ss += v[t].x * v[t].x + v[t].y * v[t].y + v[t].z * v[t].z + v[t].w * v[t].w;
    }
    #pragma unroll
    for (int off = 32; off; off >>= 1) ss += __shfl_xor(ss, off, 64);
    const float scale = 1.0f / fmaxf(sqrtf(ss), 1e-12f);
    int4 o;
    int* op = (int*)&o;
    #pragma unroll
    for (int t = 0; t < 4; ++t) {
        int lo = __builtin_amdgcn_cvt_pk_fp8_f32(v[t].x * scale, v[t].y * scale, 0, false);
        op[t]  = __builtin_amdgcn_cvt_pk_fp8_f32(v[t].z * scale, v[t].w * scale, lo, true);
    }
    ((int4*)(z + (size_t)row * DIM))[lane] = o;   // 64 lanes x 16 B = one row
}

// ---------------------------------------------------------------------------
// Kernel 2: sim = z z^T via MX-scaled fp8 MFMA (unit scales). R15 = R14 with
// ONE change: __launch_bounds__(512, 2). R14's 285-µs failure was a spill
// storm (VGPR capped at 128, WRITE_SIZE 285 MB) because mfma_scale operands
// can't ride in AGPRs; declaring 2 waves/EU (which the 64-KB LDS forces
// anyway: 1 block/CU = 8 waves = 2/SIMD) raises the budget to ~256 VGPRs
// for the ~200-reg demand (acc 128 + af 32 + bf 8 + addressing).
// Shell (R13-proven): 256x256 tile, 8 waves, 256 blocks = 1/CU, XCD 4x8
// region swizzle, XOR-swizzled LDS, fence-free finalize. K-loop: BK=128,
// single 64 KB buffer, R7's 2-barrier structure. Per wave/iter: 24
// ds_read_b128 -> 32 MX MFMAs (65536 FLOP each; matrix floor 16.6 -> 8.3 us).
// ---------------------------------------------------------------------------
__global__ __launch_bounds__(512, 2) void gemm_fused(
        const char* __restrict__ z,
        float* __restrict__ rowsum,
        float* __restrict__ positives,
        unsigned int* __restrict__ counter,
        float* __restrict__ out) {
    __shared__ char smem[65536];     // sA 32 KB (256x128B) | sB 32 KB

    // XCD-aware swizzle: id&7 = round-robin XCD; 4x8-tile region per XCD
    const int bid = blockIdx.x;
    const int xcd = bid & 7;
    const int t5  = bid >> 3;                   // 0..31 within region
    const int by  = (xcd >> 1) * 4 + (t5 & 3);
    const int bx  = (xcd & 1) * 8 + (t5 >> 2);
    const int rb  = by * 256;
    const int cb  = bx * 256;

    const int tid  = threadIdx.x;
    const int lane = tid & 63;
    const int wv   = tid >> 6;       // wave 0..7
    const int wr   = wv & 3;         // wave row (0..3) -> 64-row subtile
    const int wc   = wv >> 2;        // wave col (0..1) -> 128-col subtile
    const int hq   = lane >> 4;      // k-block 0..3 (32 B each)
    const int mn   = lane & 15;

    f32x4 acc[4][8] = {};

    // staging: chunk = 8 rows x 128 B = 1 KB; A: ci 0..31, B: ci 32..63;
    // wave wv stages ci = 8wv..8wv+7. lane l: row l>>3, slot l&7, fetches
    // K-seg (l&7)^((l>>3)&7) so LDS slot s of row r holds seg s^(r&7).
    const int lrow  = lane >> 3;
    const int lsegb = ((lane & 7) ^ (lrow & 7)) * 16;
    // frag read slots (row&7 == mn&7; 64/16/128 offsets are x8 multiples)
    const int slot0 = ((2 * hq    ) ^ (mn & 7)) * 16;
    const int slot1 = ((2 * hq + 1) ^ (mn & 7)) * 16;

    size_t goff[8];
    #pragma unroll
    for (int t = 0; t < 8; ++t) {
        const int ci = wv * 8 + t;
        const bool isB = ci >= 32;
        const int  cc  = ci & 31;
        goff[t] = (size_t)((isB ? cb : rb) + cc * 8 + lrow) * DIM + lsegb;
    }
    const int loffb = wv * 8192;     // ci*1024 (sB region starts at 32768 = ci 32)

    for (int t = 0; t < 8; ++t) {
        const int k0 = t * 128;
        #pragma unroll
        for (int c = 0; c < 8; ++c)
            load_lds16(z + goff[c] + k0, smem + loffb + c * 1024);
        __syncthreads();   // staging complete

        const char* cA = smem;
        const char* cB = smem + 32768;

        v8i af[4];
        #pragma unroll
        for (int i = 0; i < 4; ++i) {
            const char* rowA = cA + (wr * 64 + i * 16 + mn) * 128;
            int4 lo = *(const int4*)(rowA + slot0);
            int4 hi = *(const int4*)(rowA + slot1);
            af[i][0] = lo.x; af[i][1] = lo.y; af[i][2] = lo.z; af[i][3] = lo.w;
            af[i][4] = hi.x; af[i][5] = hi.y; af[i][6] = hi.z; af[i][7] = hi.w;
        }
        #pragma unroll
        for (int j = 0; j < 8; ++j) {
            const char* rowB = cB + (wc * 128 + j * 16 + mn) * 128;
            int4 lo = *(const int4*)(rowB + slot0);
            int4 hi = *(const int4*)(rowB + slot1);
            v8i bf;
            bf[0] = lo.x; bf[1] = lo.y; bf[2] = lo.z; bf[3] = lo.w;
            bf[4] = hi.x; bf[5] = hi.y; bf[6] = hi.z; bf[7] = hi.w;
            #pragma unroll
            for (int i = 0; i < 4; ++i)
                acc[i][j] = __builtin_amdgcn_mfma_scale_f32_16x16x128_f8f6f4(
                                af[i], bf, acc[i][j], 0, 0,
                                0, SCALE_ONE, 0, SCALE_ONE);
        }
        __syncthreads();   // all reads done before next overwrite
    }

    // ---- Epilogue (C/D col = lane&15, row = hq*4 + reg — shape-determined,
    //      dtype-independent incl. f8f6f4-scaled; m121-128) ----
    #pragma unroll
    for (int i = 0; i < 4; ++i) {
        #pragma unroll
        for (int reg = 0; reg < 4; ++reg) {
            const int r  = rb + wr * 64 + i * 16 + hq * 4 + reg;
            const int pc = (r + BATCH) & (TWO_B - 1);
            float local = 0.0f;
            #pragma unroll
            for (int j = 0; j < 8; ++j) {
                const int c = cb + wc * 128 + j * 16 + mn;
                const float s = acc[i][j][reg];
                if (c == pc)   // unique writer per r
                    __hip_atomic_store(&positives[r], s, __ATOMIC_RELAXED,
                                       __HIP_MEMORY_SCOPE_AGENT);
                local += (c == r) ? 0.0f : exp2f(s * INV_T_LOG2E);
            }
            local += __shfl_xor(local, 1, 64);
            local += __shfl_xor(local, 2, 64);
            local += __shfl_xor(local, 4, 64);
            local += __shfl_xor(local, 8, 64);
            if (mn == 0) atomicAdd(&rowsum[r], local);
        }
    }

    // ---- fence-free last-block finalize (R7/R8/R13, proven) ----
    __shared__ int amLast;
    __syncthreads();
    if (tid == 0) {
        unsigned int old = __hip_atomic_fetch_add(counter, 1u, __ATOMIC_RELAXED,
                                                  __HIP_MEMORY_SCOPE_AGENT);
        amLast = (old == NBLK4 - 1);
    }
    __syncthreads();
    if (amLast) {
        float acc2 = 0.0f;
        for (int r = tid; r < TWO_B; r += 512) {
            float rs = __hip_atomic_load(&rowsum[r], __ATOMIC_RELAXED,
                                         __HIP_MEMORY_SCOPE_AGENT);
            float p  = __hip_atomic_load(&positives[r], __ATOMIC_RELAXED,
                                         __HIP_MEMORY_SCOPE_AGENT);
            acc2 += logf(rs) - p * INV_T;
        }
        #pragma unroll
        for (int off = 32; off; off >>= 1) acc2 += __shfl_down(acc2, off, 64);
        __shared__ float s_part[8];
        if ((tid & 63) == 0) s_part[tid >> 6] = acc2;
        __syncthreads();
        if (tid == 0) {
            float tot = 0.0f;
            #pragma unroll
            for (int w = 0; w < 8; ++w) tot += s_part[w];
            out[0] = tot * (1.0f / TWO_B);
        }
    }
}

extern "C" void kernel_launch(void* const* d_in, const int* in_sizes, int n_in,
                              void* d_out, int out_size, void* d_ws, size_t ws_size,
                              hipStream_t stream) {
    const float* feat = (const float*)d_in[0];
    char* ws = (char*)d_ws;

    // workspace: z fp8[4096][1024] (4 MB) | rowsum f32[4096] | positives f32[4096] | counter
    char* zq              = ws;
    float* rowsum         = (float*)(ws + (size_t)TWO_B * DIM);
    float* positives      = rowsum + TWO_B;
    unsigned int* counter = (unsigned int*)(positives + TWO_B);
    float* out            = (float*)d_out;

    normalize_kernel<<<TWO_B / 4, 256, 0, stream>>>(feat, zq, rowsum, counter);
    gemm_fused<<<NBLK4, 512, 0, stream>>>(zq, rowsum, positives, counter, out);
}

// Round 16
// 96.130 us; speedup vs baseline: 2.9800x; 2.9800x over previous
//
#include <hip/hip_runtime.h>
#include <hip/hip_bf16.h>
#include <math.h>

// Problem constants
#define BATCH   2048
#define TWO_B   4096
#define DIM     1024
#define NBLK4   256           // 16x16 grid of 256x256 tiles
// 1 / (0.07 * ln(2)) : exp(s/T) = exp2(s * INV_T_LOG2E)
#define INV_T_LOG2E 20.60991907f
#define INV_T       14.285714285714286f

typedef float f32x4 __attribute__((ext_vector_type(4)));
typedef long  i64x2 __attribute__((ext_vector_type(2)));

__device__ __forceinline__ void load_lds16(const void* g, void* l) {
    __builtin_amdgcn_global_load_lds(
        (const __attribute__((address_space(1))) void*)g,
        (__attribute__((address_space(3))) void*)l,
        16, 0, 0);
}

// ---------------------------------------------------------------------------
// Kernel 1: L2-normalize 4096 rows -> fp8 e4m3 z[4096][1024] (4 MB).
// Wave-per-row; zero-inits rowsum + completion counter. No fences.
// ---------------------------------------------------------------------------
__global__ __launch_bounds__(256) void normalize_kernel(
        const float* __restrict__ feat, char* __restrict__ z,
        float* __restrict__ rowsum, unsigned int* __restrict__ counter) {
    const int lane = threadIdx.x & 63;
    const int row  = blockIdx.x * 4 + (threadIdx.x >> 6);
    if (lane == 0) rowsum[row] = 0.0f;
    if (blockIdx.x == 0 && threadIdx.x == 0) *counter = 0u;

    const float* src = feat + (row < BATCH ? (size_t)row * (2 * DIM)
                                           : (size_t)(row - BATCH) * (2 * DIM) + DIM);
    float4 v[4];
    float ss = 0.0f;
    #pragma unroll
    for (int t = 0; t < 4; ++t) {
        v[t] = ((const float4*)src)[t * 64 + lane];
        ss += v[t].x * v[t].x + v[t].y * v[t].y + v[t].z * v[t].z + v[t].w * v[t].w;
    }
    #pragma unroll
    for (int off = 32; off; off >>= 1) ss += __shfl_xor(ss, off, 64);
    const float scale = 1.0f / fmaxf(sqrtf(ss), 1e-12f);
    int4 o;
    int* op = (int*)&o;
    #pragma unroll
    for (int t = 0; t < 4; ++t) {
        int lo = __builtin_amdgcn_cvt_pk_fp8_f32(v[t].x * scale, v[t].y * scale, 0, false);
        op[t]  = __builtin_amdgcn_cvt_pk_fp8_f32(v[t].z * scale, v[t].w * scale, lo, true);
    }
    ((int4*)(z + (size_t)row * DIM))[lane] = o;   // 64 lanes x 16 B = one row
}

// ---------------------------------------------------------------------------
// Kernel 2: sim = z z^T in fp8 e4m3, plain mfma_f32_16x16x32_fp8_fp8 (acc
// rides in AGPRs — the MX-scaled variants spill: R12/R14/R15). R13-proven
// shell: 256x256 tiles, 8 waves (512 thr), BK=64 dbuf (64 KB LDS), 256
// blocks = 1/CU. Staged bytes 134 MB (the affine-model lever that took
// GEMM 44 -> ~40 us). XOR swizzle (0 conflicts), XCD 4x8 region swizzle
// (3 MB < 4 MB L2), shfl epilogue, fence-free last-block finalize.
// This is the measured source-level plateau (~41% of fp8 µbench ceiling);
// R5/R7/R9/R10/R11 showed sync/staging restructures are all neutral-or-worse.
// ---------------------------------------------------------------------------
__global__ __launch_bounds__(512) void gemm_fused(
        const char* __restrict__ z,
        float* __restrict__ rowsum,
        float* __restrict__ positives,
        unsigned int* __restrict__ counter,
        float* __restrict__ out) {
    __shared__ char smem[65536];     // buf: [sA 16K | sB 16K] x2

    // XCD-aware swizzle: id&7 = round-robin XCD; 4x8-tile region per XCD
    const int bid = blockIdx.x;
    const int xcd = bid & 7;
    const int t5  = bid >> 3;                   // 0..31 within region
    const int by  = (xcd >> 1) * 4 + (t5 & 3);
    const int bx  = (xcd & 1) * 8 + (t5 >> 2);
    const int rb  = by * 256;
    const int cb  = bx * 256;

    const int tid  = threadIdx.x;
    const int lane = tid & 63;
    const int wv   = tid >> 6;       // wave 0..7
    const int wr   = wv & 3;         // wave row (0..3) -> 64-row subtile
    const int wc   = wv >> 2;        // wave col (0..1) -> 128-col subtile
    const int q    = lane >> 4;      // quad 0..3
    const int mn   = lane & 15;

    f32x4 acc[4][8] = {};

    const int lrow  = lane >> 2;                       // row within 16-row chunk
    const int lsegb = ((lane & 3) ^ ((lane >> 3) & 3)) * 16;   // fetch-side XOR swizzle
    const int rslot = (q ^ ((mn >> 1) & 3)) * 16;      // byte offset in 64-B row

    // staging: 32 chunks of 16 rows x 64 B (A: ci 0..15, B: ci 16..31);
    // wave wv stages ci = 4wv..4wv+3.
    size_t goff[4];
    int    loff[4];
    #pragma unroll
    for (int t = 0; t < 4; ++t) {
        const int ci = wv * 4 + t;
        const bool isB = ci >= 16;
        const int  cc  = ci & 15;
        goff[t] = (size_t)((isB ? cb : rb) + cc * 16 + lrow) * DIM + lsegb;
        loff[t] = (isB ? 16384 : 0) + cc * 1024;
    }

    // preload K-tile 0 into buffer 0
    #pragma unroll
    for (int t = 0; t < 4; ++t)
        load_lds16(z + goff[t], smem + loff[t]);
    __syncthreads();

    int cur = 0;
    for (int k0 = 64; k0 <= DIM; k0 += 64) {
        if (k0 < DIM) {   // prefetch next K-tile into the other buffer
            const int nxt = cur ^ 1;
            #pragma unroll
            for (int t = 0; t < 4; ++t)
                load_lds16(z + goff[t] + k0, smem + nxt * 32768 + loff[t]);
        }
        const char* cA = smem + cur * 32768;
        const char* cB = cA + 16384;

        i64x2 af[4], bf[8];
        #pragma unroll
        for (int i = 0; i < 4; ++i)
            af[i] = *(const i64x2*)&cA[(wr * 64 + i * 16 + mn) * 64 + rslot];
        #pragma unroll
        for (int j = 0; j < 8; ++j)
            bf[j] = *(const i64x2*)&cB[(wc * 128 + j * 16 + mn) * 64 + rslot];
        #pragma unroll
        for (int i = 0; i < 4; ++i)
            #pragma unroll
            for (int j = 0; j < 8; ++j) {
                acc[i][j] = __builtin_amdgcn_mfma_f32_16x16x32_fp8_fp8(
                                af[i].x, bf[j].x, acc[i][j], 0, 0, 0);
                acc[i][j] = __builtin_amdgcn_mfma_f32_16x16x32_fp8_fp8(
                                af[i].y, bf[j].y, acc[i][j], 0, 0, 0);
            }
        __syncthreads();
        cur ^= 1;
    }

    // ---- Epilogue (shfl; C/D col = lane&15, row = q*4 + reg) ----
    #pragma unroll
    for (int i = 0; i < 4; ++i) {
        #pragma unroll
        for (int reg = 0; reg < 4; ++reg) {
            const int r  = rb + wr * 64 + i * 16 + q * 4 + reg;
            const int pc = (r + BATCH) & (TWO_B - 1);
            float local = 0.0f;
            #pragma unroll
            for (int j = 0; j < 8; ++j) {
                const int c = cb + wc * 128 + j * 16 + mn;
                const float s = acc[i][j][reg];
                if (c == pc)   // unique writer per r
                    __hip_atomic_store(&positives[r], s, __ATOMIC_RELAXED,
                                       __HIP_MEMORY_SCOPE_AGENT);
                local += (c == r) ? 0.0f : exp2f(s * INV_T_LOG2E);
            }
            local += __shfl_xor(local, 1, 64);
            local += __shfl_xor(local, 2, 64);
            local += __shfl_xor(local, 4, 64);
            local += __shfl_xor(local, 8, 64);
            if (mn == 0) atomicAdd(&rowsum[r], local);
        }
    }

    // ---- fence-free last-block finalize (R7/R8/R13, proven) ----
    __shared__ int amLast;
    __syncthreads();
    if (tid == 0) {
        unsigned int old = __hip_atomic_fetch_add(counter, 1u, __ATOMIC_RELAXED,
                                                  __HIP_MEMORY_SCOPE_AGENT);
        amLast = (old == NBLK4 - 1);
    }
    __syncthreads();
    if (amLast) {
        float acc2 = 0.0f;
        for (int r = tid; r < TWO_B; r += 512) {
            float rs = __hip_atomic_load(&rowsum[r], __ATOMIC_RELAXED,
                                         __HIP_MEMORY_SCOPE_AGENT);
            float p  = __hip_atomic_load(&positives[r], __ATOMIC_RELAXED,
                                         __HIP_MEMORY_SCOPE_AGENT);
            acc2 += logf(rs) - p * INV_T;
        }
        #pragma unroll
        for (int off = 32; off; off >>= 1) acc2 += __shfl_down(acc2, off, 64);
        __shared__ float s_part[8];
        if ((tid & 63) == 0) s_part[tid >> 6] = acc2;
        __syncthreads();
        if (tid == 0) {
            float tot = 0.0f;
            #pragma unroll
            for (int w = 0; w < 8; ++w) tot += s_part[w];
            out[0] = tot * (1.0f / TWO_B);
        }
    }
}

extern "C" void kernel_launch(void* const* d_in, const int* in_sizes, int n_in,
                              void* d_out, int out_size, void* d_ws, size_t ws_size,
                              hipStream_t stream) {
    const float* feat = (const float*)d_in[0];
    char* ws = (char*)d_ws;

    // workspace: z fp8[4096][1024] (4 MB) | rowsum f32[4096] | positives f32[4096] | counter
    char* zq              = ws;
    float* rowsum         = (float*)(ws + (size_t)TWO_B * DIM);
    float* positives      = rowsum + TWO_B;
    unsigned int* counter = (unsigned int*)(positives + TWO_B);
    float* out            = (float*)d_out;

    normalize_kernel<<<TWO_B / 4, 256, 0, stream>>>(feat, zq, rowsum, counter);
    gemm_fused<<<NBLK4, 512, 0, stream>>>(zq, rowsum, positives, counter, out);
}